// Round 1
// baseline (698.039 us; speedup 1.0000x reference)
//
#include <hip/hip_runtime.h>

#define HID 512
#define NB 20000
#define NNODES 100000
#define NBM 157            // ceil(20000/128)
#define MP (NBM*128)       // 20096 padded rows
#define NC 2048            // virtual gate columns: [rz 1024 | i_n 512 | h_n 512]

typedef unsigned short u16;
typedef __bf16 bf16x8 __attribute__((ext_vector_type(8)));
typedef float f32x4 __attribute__((ext_vector_type(4)));

__device__ __forceinline__ u16 f2bf(float f) {
  union { float f; unsigned u; } v; v.f = f;
  unsigned r = v.u + 0x7fffu + ((v.u >> 16) & 1u);   // round-nearest-even
  return (u16)(r >> 16);
}
__device__ __forceinline__ float bf2f(u16 b) {
  union { unsigned u; float f; } v; v.u = ((unsigned)b) << 16;
  return v.f;
}

// ---------------- weight prep: Bt[j][k] = B^T panels with n-gate split ----------------
// Layer0: K=1536 (x:1024 | h:512). cols j: [0,1024) rz combined; [1024,1536) i_n; [1536,2048) h_n
__global__ void prep_bt0(const float* __restrict__ Wih, const float* __restrict__ Whh,
                         u16* __restrict__ Bt) {
  int idx = blockIdx.x * 256 + threadIdx.x;          // 2048*384
  if (idx >= 2048 * 384) return;
  int j = idx / 384;
  int k = (idx % 384) * 4;
  float4 v = make_float4(0.f, 0.f, 0.f, 0.f);
  if (j < 1024) {
    v = (k < 1024) ? *(const float4*)(Wih + (size_t)j * 1024 + k)
                   : *(const float4*)(Whh + (size_t)j * 512 + (k - 1024));
  } else if (j < 1536) {                             // i_n: gate row = j
    if (k < 1024) v = *(const float4*)(Wih + (size_t)j * 1024 + k);
  } else {                                           // h_n: gate row = j-512
    if (k >= 1024) v = *(const float4*)(Whh + (size_t)(j - 512) * 512 + (k - 1024));
  }
  ushort4 b; b.x = f2bf(v.x); b.y = f2bf(v.y); b.z = f2bf(v.z); b.w = f2bf(v.w);
  *(ushort4*)(Bt + (size_t)j * 1536 + k) = b;
}

// Layer1: K=1024 (x=h_new0:512 | h:512)
__global__ void prep_bt1(const float* __restrict__ Wih, const float* __restrict__ Whh,
                         u16* __restrict__ Bt) {
  int idx = blockIdx.x * 256 + threadIdx.x;          // 2048*256
  if (idx >= 2048 * 256) return;
  int j = idx / 256;
  int k = (idx % 256) * 4;
  float4 v = make_float4(0.f, 0.f, 0.f, 0.f);
  if (j < 1024) {
    v = (k < 512) ? *(const float4*)(Wih + (size_t)j * 512 + k)
                  : *(const float4*)(Whh + (size_t)j * 512 + (k - 512));
  } else if (j < 1536) {
    if (k < 512) v = *(const float4*)(Wih + (size_t)j * 512 + k);
  } else {
    if (k >= 512) v = *(const float4*)(Whh + (size_t)(j - 512) * 512 + (k - 512));
  }
  ushort4 b; b.x = f2bf(v.x); b.y = f2bf(v.y); b.z = f2bf(v.z); b.w = f2bf(v.w);
  *(ushort4*)(Bt + (size_t)j * 1024 + k) = b;
}

// ---------------- A prep: A0 = [conv | static[nid] | h0row0] bf16; A1 right half = h0row1 ----
__global__ void prep_a(const float* __restrict__ conv, const float* __restrict__ stat,
                       const float* __restrict__ dyn, const int* __restrict__ nids,
                       u16* __restrict__ A0, u16* __restrict__ A1) {
  int idx = blockIdx.x * 256 + threadIdx.x;          // MP*512 (2048 cols / 4)
  int n = idx >> 9;
  int c = (idx & 511) * 4;
  if (n >= MP) return;
  float4 v = make_float4(0.f, 0.f, 0.f, 0.f);
  if (n < NB) {
    size_t nid = (size_t)nids[n];
    if (c < 512)        v = *(const float4*)(conv + (size_t)n * 512 + c);
    else if (c < 1024)  v = *(const float4*)(stat + nid * 512 + (c - 512));
    else if (c < 1536)  v = *(const float4*)(dyn + nid * 1024 + (c - 1024));        // h row 0
    else                v = *(const float4*)(dyn + nid * 1024 + 512 + (c - 1536));  // h row 1
  }
  ushort4 b; b.x = f2bf(v.x); b.y = f2bf(v.y); b.z = f2bf(v.z); b.w = f2bf(v.w);
  if (c < 1536) *(ushort4*)(A0 + (size_t)n * 1536 + c) = b;
  else          *(ushort4*)(A1 + (size_t)n * 1024 + (c - 1024)) = b;
  if (n >= NB && c < 512) *(ushort4*)(A1 + (size_t)n * 1024 + c) = b;  // zero pad rows
}

// ---------------- GEMM: C[MP][2048] = A[MP][K] @ Bt[2048][K]^T  (m97-style 128x128) ----
template <int K>
__global__ __launch_bounds__(256)
void gemm_nt(const u16* __restrict__ A, const u16* __restrict__ Bt, float* __restrict__ C) {
  __shared__ u16 sA[128 * 32];
  __shared__ u16 sB[128 * 32];
  const int NBN = 16, G = 8;
  int bid = blockIdx.x;
  int g = bid / (G * NBN);
  int rem = bid - g * (G * NBN);
  int gr = NBM - g * G; if (gr > G) gr = G;          // rows in this supergroup
  int brow = g * G + rem % gr;
  int bcol = rem / gr;

  int t = threadIdx.x;
  int lane = t & 63;
  int wave = t >> 6;
  int wr = wave >> 1, wc = wave & 1;                 // 2x2 waves -> 64x64 each

  f32x4 acc[4][4] = {};

  const u16* Abase = A + (size_t)(brow * 128) * K;
  const u16* Bbase = Bt + (size_t)(bcol * 128) * K;

  for (int ks = 0; ks < K; ks += 32) {
#pragma unroll
    for (int i = 0; i < 2; ++i) {
      int c = t + i * 256;                           // 16B chunk id, linear in lane
      int row = c >> 2;
      int ko = (c & 3) * 8;                          // ushort offset
      const u16* ga = Abase + (size_t)row * K + ks + ko;
      const u16* gb = Bbase + (size_t)row * K + ks + ko;
      __builtin_amdgcn_global_load_lds((const __attribute__((address_space(1))) void*)ga,
                                       (__attribute__((address_space(3))) void*)&sA[c * 8],
                                       16, 0, 0);
      __builtin_amdgcn_global_load_lds((const __attribute__((address_space(1))) void*)gb,
                                       (__attribute__((address_space(3))) void*)&sB[c * 8],
                                       16, 0, 0);
    }
    __syncthreads();

    bf16x8 af[4], bfr[4];
#pragma unroll
    for (int m = 0; m < 4; ++m) {
      int r = wr * 64 + m * 16 + (lane & 15);
      af[m] = *(const bf16x8*)&sA[r * 32 + (lane >> 4) * 8];
    }
#pragma unroll
    for (int n = 0; n < 4; ++n) {
      int cx = wc * 64 + n * 16 + (lane & 15);
      bfr[n] = *(const bf16x8*)&sB[cx * 32 + (lane >> 4) * 8];
    }
#pragma unroll
    for (int m = 0; m < 4; ++m)
#pragma unroll
      for (int n = 0; n < 4; ++n)
        acc[m][n] = __builtin_amdgcn_mfma_f32_16x16x32_bf16(af[m], bfr[n], acc[m][n], 0, 0, 0);
    __syncthreads();
  }

  int fr = lane & 15, fq = lane >> 4;
#pragma unroll
  for (int m = 0; m < 4; ++m) {
    int rbase = brow * 128 + wr * 64 + m * 16 + fq * 4;
#pragma unroll
    for (int n = 0; n < 4; ++n) {
      int cg = bcol * 128 + wc * 64 + n * 16 + fr;
#pragma unroll
      for (int r = 0; r < 4; ++r)
        C[(size_t)(rbase + r) * NC + cg] = acc[m][n][r];
    }
  }
}

// ---------------- gate epilogue: h' = (1-z)*n + z*h ----------------
__global__ void gates(const float* __restrict__ C, const float* __restrict__ bih,
                      const float* __restrict__ bhh, const float* __restrict__ dyn,
                      const int* __restrict__ nids, int layer,
                      u16* __restrict__ out, int ostride) {
  int idx = blockIdx.x * 256 + threadIdx.x;
  if (idx >= NB * 512) return;
  int n = idx >> 9, j = idx & 511;
  const float* Cr = C + (size_t)n * NC;
  float ir = Cr[j] + bih[j] + bhh[j];
  float iz = Cr[512 + j] + bih[512 + j] + bhh[512 + j];
  float in_ = Cr[1024 + j] + bih[1024 + j];
  float hn  = Cr[1536 + j] + bhh[1024 + j];
  float r = 1.f / (1.f + __expf(-ir));
  float z = 1.f / (1.f + __expf(-iz));
  float nn = tanhf(fmaf(r, hn, in_));
  float h  = dyn[(size_t)nids[n] * 1024 + (size_t)layer * 512 + j];
  float hp = (1.f - z) * nn + z * h;
  out[(size_t)n * ostride + j] = f2bf(hp);
}

// ---------------- full-table copy + scatter of updated rows ----------------
__global__ void copy_table(const float4* __restrict__ src, float4* __restrict__ dst) {
  const size_t total = (size_t)NNODES * 256;         // 100000*1024/4
  for (size_t i = (size_t)blockIdx.x * 256 + threadIdx.x; i < total;
       i += (size_t)gridDim.x * 256)
    dst[i] = src[i];
}

__global__ void scatter_rows(const u16* __restrict__ A1, const u16* __restrict__ H1,
                             const int* __restrict__ nids, float* __restrict__ out) {
  int idx = blockIdx.x * 256 + threadIdx.x;          // NB*256
  if (idx >= NB * 256) return;
  int n = idx >> 8;
  int c = (idx & 255) * 4;
  const u16* src = (c < 512) ? (A1 + (size_t)n * 1024 + c)
                             : (H1 + (size_t)n * 512 + (c - 512));
  float4 v; v.x = bf2f(src[0]); v.y = bf2f(src[1]); v.z = bf2f(src[2]); v.w = bf2f(src[3]);
  *(float4*)(out + (size_t)nids[n] * 1024 + c) = v;
}

extern "C" void kernel_launch(void* const* d_in, const int* in_sizes, int n_in,
                              void* d_out, int out_size, void* d_ws, size_t ws_size,
                              hipStream_t stream) {
  const float* conv = (const float*)d_in[0];
  const float* stat = (const float*)d_in[1];
  const float* dyn  = (const float*)d_in[2];
  const float* Wih0 = (const float*)d_in[3];
  const float* Whh0 = (const float*)d_in[4];
  const float* bih0 = (const float*)d_in[5];
  const float* bhh0 = (const float*)d_in[6];
  const float* Wih1 = (const float*)d_in[7];
  const float* Whh1 = (const float*)d_in[8];
  const float* bih1 = (const float*)d_in[9];
  const float* bhh1 = (const float*)d_in[10];
  const int*   nids = (const int*)d_in[11];
  float* out = (float*)d_out;

  char* ws = (char*)d_ws;
  u16* A0  = (u16*)(ws);                    // MP*1536*2 = 61,734,912
  u16* A1  = (u16*)(ws + 61734912);         // MP*1024*2 = 41,156,608
  u16* Bt0 = (u16*)(ws + 102891520);        // 2048*1536*2 = 6,291,456
  u16* Bt1 = (u16*)(ws + 109182976);        // 2048*1024*2 = 4,194,304
  u16* H1  = (u16*)(ws + 113377280);        // MP*512*2
  float* C = (float*)d_out;                 // [MP][2048] f32 scratch, overwritten by copy later

  prep_bt0<<<3072, 256, 0, stream>>>(Wih0, Whh0, Bt0);
  prep_bt1<<<2048, 256, 0, stream>>>(Wih1, Whh1, Bt1);
  prep_a<<<(MP * 512) / 256, 256, 0, stream>>>(conv, stat, dyn, nids, A0, A1);

  gemm_nt<1536><<<NBM * 16, 256, 0, stream>>>(A0, Bt0, C);
  gates<<<(NB * 512) / 256, 256, 0, stream>>>(C, bih0, bhh0, dyn, nids, 0, A1, 1024);

  gemm_nt<1024><<<NBM * 16, 256, 0, stream>>>(A1, Bt1, C);
  gates<<<(NB * 512) / 256, 256, 0, stream>>>(C, bih1, bhh1, dyn, nids, 1, H1, 512);

  copy_table<<<4096, 256, 0, stream>>>((const float4*)dyn, (float4*)out);
  scatter_rows<<<(NB * 256) / 256, 256, 0, stream>>>(A1, H1, nids, out);
}

// Round 2
// 642.953 us; speedup vs baseline: 1.0857x; 1.0857x over previous
//
#include <hip/hip_runtime.h>

#define HID 512
#define NB 20000
#define NNODES 100000
#define NBM 157            // ceil(20000/128)
#define MP (NBM*128)       // 20096 padded rows
#define NBITW 3125         // ceil(100000/32)

typedef unsigned short u16;
typedef __bf16 bf16x8 __attribute__((ext_vector_type(8)));
typedef float f32x4 __attribute__((ext_vector_type(4)));

__device__ __forceinline__ u16 f2bf(float f) {
  union { float f; unsigned u; } v; v.f = f;
  unsigned r = v.u + 0x7fffu + ((v.u >> 16) & 1u);   // round-nearest-even
  return (u16)(r >> 16);
}
__device__ __forceinline__ float bf2f(u16 b) {
  union { unsigned u; float f; } v; v.u = ((unsigned)b) << 16;
  return v.f;
}

// ---------------- weight prep: interleaved B^T: row jg = j*4 + gate, gate in {r,z,i_n,h_n} ----
// Layer0: K=1536 (x:1024 | h:512)
__global__ void prep_bt0i(const float* __restrict__ Wih, const float* __restrict__ Whh,
                          u16* __restrict__ Bt) {
  int idx = blockIdx.x * 256 + threadIdx.x;          // 2048*384
  if (idx >= 2048 * 384) return;
  int jg = idx / 384;
  int k = (idx % 384) * 4;
  int j = jg >> 2, g = jg & 3;
  float4 v = make_float4(0.f, 0.f, 0.f, 0.f);
  if (g < 2) {                                       // r or z: full K
    int row = g * 512 + j;
    v = (k < 1024) ? *(const float4*)(Wih + (size_t)row * 1024 + k)
                   : *(const float4*)(Whh + (size_t)row * 512 + (k - 1024));
  } else if (g == 2) {                               // i_n: x part only
    if (k < 1024) v = *(const float4*)(Wih + (size_t)(1024 + j) * 1024 + k);
  } else {                                           // h_n: h part only
    if (k >= 1024) v = *(const float4*)(Whh + (size_t)(1024 + j) * 512 + (k - 1024));
  }
  ushort4 b; b.x = f2bf(v.x); b.y = f2bf(v.y); b.z = f2bf(v.z); b.w = f2bf(v.w);
  *(ushort4*)(Bt + (size_t)jg * 1536 + k) = b;
}

// Layer1: K=1024 (x=h_new0:512 | h:512)
__global__ void prep_bt1i(const float* __restrict__ Wih, const float* __restrict__ Whh,
                          u16* __restrict__ Bt) {
  int idx = blockIdx.x * 256 + threadIdx.x;          // 2048*256
  if (idx >= 2048 * 256) return;
  int jg = idx / 256;
  int k = (idx % 256) * 4;
  int j = jg >> 2, g = jg & 3;
  float4 v = make_float4(0.f, 0.f, 0.f, 0.f);
  if (g < 2) {
    int row = g * 512 + j;
    v = (k < 512) ? *(const float4*)(Wih + (size_t)row * 512 + k)
                  : *(const float4*)(Whh + (size_t)row * 512 + (k - 512));
  } else if (g == 2) {
    if (k < 512) v = *(const float4*)(Wih + (size_t)(1024 + j) * 512 + k);
  } else {
    if (k >= 512) v = *(const float4*)(Whh + (size_t)(1024 + j) * 512 + (k - 512));
  }
  ushort4 b; b.x = f2bf(v.x); b.y = f2bf(v.y); b.z = f2bf(v.z); b.w = f2bf(v.w);
  *(ushort4*)(Bt + (size_t)jg * 1024 + k) = b;
}

// ---------------- A prep: A0 = [conv | static[nid] | h0row0] bf16; A1 right half = h0row1 ----
__global__ void prep_a(const float* __restrict__ conv, const float* __restrict__ stat,
                       const float* __restrict__ dyn, const int* __restrict__ nids,
                       u16* __restrict__ A0, u16* __restrict__ A1) {
  int idx = blockIdx.x * 256 + threadIdx.x;          // MP*512 (2048 cols / 4)
  int n = idx >> 9;
  int c = (idx & 511) * 4;
  if (n >= MP) return;
  float4 v = make_float4(0.f, 0.f, 0.f, 0.f);
  if (n < NB) {
    size_t nid = (size_t)nids[n];
    if (c < 512)        v = *(const float4*)(conv + (size_t)n * 512 + c);
    else if (c < 1024)  v = *(const float4*)(stat + nid * 512 + (c - 512));
    else if (c < 1536)  v = *(const float4*)(dyn + nid * 1024 + (c - 1024));        // h row 0
    else                v = *(const float4*)(dyn + nid * 1024 + 512 + (c - 1536));  // h row 1
  }
  ushort4 b; b.x = f2bf(v.x); b.y = f2bf(v.y); b.z = f2bf(v.z); b.w = f2bf(v.w);
  if (c < 1536) *(ushort4*)(A0 + (size_t)n * 1536 + c) = b;
  else          *(ushort4*)(A1 + (size_t)n * 1024 + (c - 1024)) = b;
  if (n >= NB && c < 512) *(ushort4*)(A1 + (size_t)n * 1024 + c) = b;  // zero pad rows
}

// ---------------- fused GEMM + GRU gate epilogue ----------------
// C-tile cols are jg = j*4+gate; epilogue exchanges gates across 4 adjacent lanes via shfl_xor
template <int K, int LAYER>
__global__ __launch_bounds__(256)
void gemm_fused(const u16* __restrict__ A, const u16* __restrict__ Bt,
                const float* __restrict__ bih, const float* __restrict__ bhh,
                const u16* __restrict__ hsrc, int hstride,
                const int* __restrict__ nids,
                u16* __restrict__ A1out, float* __restrict__ out) {
  __shared__ u16 sA[128 * 32];
  __shared__ u16 sB[128 * 32];
  const int NBN = 16, G = 8;
  int bid = blockIdx.x;
  int g8 = bid / (G * NBN);
  int rem = bid - g8 * (G * NBN);
  int gr = NBM - g8 * G; if (gr > G) gr = G;
  int brow = g8 * G + rem % gr;
  int bcol = rem / gr;

  int t = threadIdx.x;
  int lane = t & 63;
  int wave = t >> 6;
  int wr = wave >> 1, wc = wave & 1;                 // 2x2 waves -> 64x64 each

  f32x4 acc[4][4] = {};

  const u16* Abase = A + (size_t)(brow * 128) * K;
  const u16* Bbase = Bt + (size_t)(bcol * 128) * K;

  for (int ks = 0; ks < K; ks += 32) {
#pragma unroll
    for (int i = 0; i < 2; ++i) {
      int c = t + i * 256;
      int row = c >> 2;
      int ko = (c & 3) * 8;
      const u16* ga = Abase + (size_t)row * K + ks + ko;
      const u16* gb = Bbase + (size_t)row * K + ks + ko;
      __builtin_amdgcn_global_load_lds((const __attribute__((address_space(1))) void*)ga,
                                       (__attribute__((address_space(3))) void*)&sA[c * 8],
                                       16, 0, 0);
      __builtin_amdgcn_global_load_lds((const __attribute__((address_space(1))) void*)gb,
                                       (__attribute__((address_space(3))) void*)&sB[c * 8],
                                       16, 0, 0);
    }
    __syncthreads();

    bf16x8 af[4], bfr[4];
#pragma unroll
    for (int m = 0; m < 4; ++m) {
      int r = wr * 64 + m * 16 + (lane & 15);
      af[m] = *(const bf16x8*)&sA[r * 32 + (lane >> 4) * 8];
    }
#pragma unroll
    for (int n = 0; n < 4; ++n) {
      int cx = wc * 64 + n * 16 + (lane & 15);
      bfr[n] = *(const bf16x8*)&sB[cx * 32 + (lane >> 4) * 8];
    }
#pragma unroll
    for (int m = 0; m < 4; ++m)
#pragma unroll
      for (int n = 0; n < 4; ++n)
        acc[m][n] = __builtin_amdgcn_mfma_f32_16x16x32_bf16(af[m], bfr[n], acc[m][n], 0, 0, 0);
    __syncthreads();
  }

  // ---- fused gate epilogue ----
  int fr = lane & 15, fq = lane >> 4;
  int gg = fr & 3;                                   // gate of this lane's column
  int jj = fr >> 2;                                  // j offset within 4-group

  float bias[4];
#pragma unroll
  for (int n = 0; n < 4; ++n) {
    int j = bcol * 32 + wc * 16 + n * 4 + jj;
    bias[n] = (gg == 0) ? bih[j] + bhh[j]
            : (gg == 1) ? bih[512 + j] + bhh[512 + j]
            : (gg == 2) ? bih[1024 + j] : bhh[1024 + j];
  }

#pragma unroll
  for (int m = 0; m < 4; ++m) {
    int rbase = brow * 128 + wr * 64 + m * 16 + fq * 4;
#pragma unroll
    for (int n = 0; n < 4; ++n) {
      int j = bcol * 32 + wc * 16 + n * 4 + jj;
#pragma unroll
      for (int r = 0; r < 4; ++r) {
        float v = acc[m][n][r] + bias[n];
        // butterfly: gather all 4 gate values into every lane of the quad
        float w1 = __shfl_xor(v, 1);
        float e  = (gg & 1) ? w1 : v;                // even gate of pair
        float o  = (gg & 1) ? v : w1;                // odd gate of pair
        float e2 = __shfl_xor(e, 2);
        float o2 = __shfl_xor(o, 2);
        float vr = (gg & 2) ? e2 : e;                // gate 0: r
        float vi = (gg & 2) ? e : e2;                // gate 2: i_n
        float vz = (gg & 2) ? o2 : o;                // gate 1: z
        float vh = (gg & 2) ? o : o2;                // gate 3: h_n
        int row = rbase + r;
        if (gg == 0 && row < NB) {
          float rr = 1.f / (1.f + __expf(-vr));
          float zz = 1.f / (1.f + __expf(-vz));
          float nn = tanhf(fmaf(rr, vh, vi));
          float h  = bf2f(hsrc[(size_t)row * hstride + j]);
          float hp = (1.f - zz) * nn + zz * h;
          if (LAYER == 0) A1out[(size_t)row * 1024 + j] = f2bf(hp);
          out[(size_t)nids[row] * 1024 + LAYER * 512 + j] = hp;
        }
      }
    }
  }
}

// ---------------- bitmap + copy of non-updated rows ----------------
__global__ void zero_bits(unsigned* __restrict__ bits) {
  int i = blockIdx.x * 256 + threadIdx.x;
  if (i < NBITW) bits[i] = 0;
}
__global__ void set_bits(const int* __restrict__ nids, unsigned* __restrict__ bits) {
  int i = blockIdx.x * 256 + threadIdx.x;
  if (i < NB) {
    int nid = nids[i];
    atomicOr(&bits[nid >> 5], 1u << (nid & 31));
  }
}
__global__ void copy_skip(const float4* __restrict__ src, float4* __restrict__ dst,
                          const unsigned* __restrict__ bits) {
  const size_t total = (size_t)NNODES * 256;         // 100000*1024/4
  for (size_t i = (size_t)blockIdx.x * 256 + threadIdx.x; i < total;
       i += (size_t)gridDim.x * 256) {
    int row = (int)(i >> 8);
    if (!((bits[row >> 5] >> (row & 31)) & 1u)) dst[i] = src[i];
  }
}

extern "C" void kernel_launch(void* const* d_in, const int* in_sizes, int n_in,
                              void* d_out, int out_size, void* d_ws, size_t ws_size,
                              hipStream_t stream) {
  const float* conv = (const float*)d_in[0];
  const float* stat = (const float*)d_in[1];
  const float* dyn  = (const float*)d_in[2];
  const float* Wih0 = (const float*)d_in[3];
  const float* Whh0 = (const float*)d_in[4];
  const float* bih0 = (const float*)d_in[5];
  const float* bhh0 = (const float*)d_in[6];
  const float* Wih1 = (const float*)d_in[7];
  const float* Whh1 = (const float*)d_in[8];
  const float* bih1 = (const float*)d_in[9];
  const float* bhh1 = (const float*)d_in[10];
  const int*   nids = (const int*)d_in[11];
  float* out = (float*)d_out;

  char* ws = (char*)d_ws;
  u16* A0  = (u16*)(ws);                    // MP*1536*2 = 61,734,912
  u16* A1  = (u16*)(ws + 61734912);         // MP*1024*2 = 41,156,608
  u16* Bt0 = (u16*)(ws + 102891520);        // 2048*1536*2 = 6,291,456
  u16* Bt1 = (u16*)(ws + 109182976);        // 2048*1024*2 = 4,194,304
  unsigned* bits = (unsigned*)(ws + 113377280);  // 12,500 B

  prep_bt0i<<<3072, 256, 0, stream>>>(Wih0, Whh0, Bt0);
  prep_bt1i<<<2048, 256, 0, stream>>>(Wih1, Whh1, Bt1);
  prep_a<<<(MP * 512) / 256, 256, 0, stream>>>(conv, stat, dyn, nids, A0, A1);

  // layer 0: h source = A0 cols [1024,1536) (h0 row 0), stride 1536
  gemm_fused<1536, 0><<<NBM * 16, 256, 0, stream>>>(A0, Bt0, bih0, bhh0,
                                                    A0 + 1024, 1536, nids, A1, out);
  // layer 1: h source = A1 cols [512,1024) (h0 row 1), stride 1024
  gemm_fused<1024, 1><<<NBM * 16, 256, 0, stream>>>(A1, Bt1, bih1, bhh1,
                                                    A1 + 512, 1024, nids, (u16*)nullptr, out);

  zero_bits<<<(NBITW + 255) / 256, 256, 0, stream>>>(bits);
  set_bits<<<(NB + 255) / 256, 256, 0, stream>>>(nids, bits);
  copy_skip<<<4096, 256, 0, stream>>>((const float4*)dyn, (float4*)out, bits);
}

// Round 3
// 527.324 us; speedup vs baseline: 1.3237x; 1.2193x over previous
//
#include <hip/hip_runtime.h>

#define NB 20000
#define NNODES 100000
#define MB2 79              // ceil(20000/256)
#define MP2 (MB2*256)       // 20224 padded rows

typedef unsigned short u16;
typedef __bf16 bf16x8 __attribute__((ext_vector_type(8)));
typedef float f32x4 __attribute__((ext_vector_type(4)));

__device__ __forceinline__ u16 f2bf(float f) {
  union { float f; unsigned u; } v; v.f = f;
  unsigned r = v.u + 0x7fffu + ((v.u >> 16) & 1u);
  return (u16)(r >> 16);
}
__device__ __forceinline__ float bf2f(u16 b) {
  union { unsigned u; float f; } v; v.u = ((unsigned)b) << 16;
  return v.f;
}

template <int N> __device__ __forceinline__ void vmwaitc() {
  if constexpr (N == 0) asm volatile("s_waitcnt vmcnt(0)" ::: "memory");
  else if constexpr (N == 2) asm volatile("s_waitcnt vmcnt(2)" ::: "memory");
  else if constexpr (N == 4) asm volatile("s_waitcnt vmcnt(4)" ::: "memory");
  else asm volatile("s_waitcnt vmcnt(8)" ::: "memory");
  __builtin_amdgcn_sched_barrier(0);
}
__device__ __forceinline__ void bar() {
  __builtin_amdgcn_sched_barrier(0);
  __builtin_amdgcn_s_barrier();
  __builtin_amdgcn_sched_barrier(0);
}

// ---------------- weight prep: interleaved B^T rows jg = j*4 + gate {r,z,i_n,h_n} ----------
__global__ void prep_bt0i(const float* __restrict__ Wih, const float* __restrict__ Whh,
                          u16* __restrict__ Bt) {
  int idx = blockIdx.x * 256 + threadIdx.x;          // 2048*384
  if (idx >= 2048 * 384) return;
  int jg = idx / 384;
  int k = (idx % 384) * 4;
  int j = jg >> 2, g = jg & 3;
  float4 v = make_float4(0.f, 0.f, 0.f, 0.f);
  if (g < 2) {
    int row = g * 512 + j;
    v = (k < 1024) ? *(const float4*)(Wih + (size_t)row * 1024 + k)
                   : *(const float4*)(Whh + (size_t)row * 512 + (k - 1024));
  } else if (g == 2) {
    if (k < 1024) v = *(const float4*)(Wih + (size_t)(1024 + j) * 1024 + k);
  } else {
    if (k >= 1024) v = *(const float4*)(Whh + (size_t)(1024 + j) * 512 + (k - 1024));
  }
  ushort4 b; b.x = f2bf(v.x); b.y = f2bf(v.y); b.z = f2bf(v.z); b.w = f2bf(v.w);
  *(ushort4*)(Bt + (size_t)jg * 1536 + k) = b;
}

__global__ void prep_bt1i(const float* __restrict__ Wih, const float* __restrict__ Whh,
                          u16* __restrict__ Bt) {
  int idx = blockIdx.x * 256 + threadIdx.x;          // 2048*256
  if (idx >= 2048 * 256) return;
  int jg = idx / 256;
  int k = (idx % 256) * 4;
  int j = jg >> 2, g = jg & 3;
  float4 v = make_float4(0.f, 0.f, 0.f, 0.f);
  if (g < 2) {
    int row = g * 512 + j;
    v = (k < 512) ? *(const float4*)(Wih + (size_t)row * 512 + k)
                  : *(const float4*)(Whh + (size_t)row * 512 + (k - 512));
  } else if (g == 2) {
    if (k < 512) v = *(const float4*)(Wih + (size_t)(1024 + j) * 512 + k);
  } else {
    if (k >= 512) v = *(const float4*)(Whh + (size_t)(1024 + j) * 512 + (k - 512));
  }
  ushort4 b; b.x = f2bf(v.x); b.y = f2bf(v.y); b.z = f2bf(v.z); b.w = f2bf(v.w);
  *(ushort4*)(Bt + (size_t)jg * 1024 + k) = b;
}

// ---------------- A prep ----------------
__global__ void prep_a(const float* __restrict__ conv, const float* __restrict__ stat,
                       const float* __restrict__ dyn, const int* __restrict__ nids,
                       u16* __restrict__ A0, u16* __restrict__ A1) {
  int idx = blockIdx.x * 256 + threadIdx.x;          // MP2*512
  int n = idx >> 9;
  int c = (idx & 511) * 4;
  if (n >= MP2) return;
  float4 v = make_float4(0.f, 0.f, 0.f, 0.f);
  if (n < NB) {
    size_t nid = (size_t)nids[n];
    if (c < 512)        v = *(const float4*)(conv + (size_t)n * 512 + c);
    else if (c < 1024)  v = *(const float4*)(stat + nid * 512 + (c - 512));
    else if (c < 1536)  v = *(const float4*)(dyn + nid * 1024 + (c - 1024));
    else                v = *(const float4*)(dyn + nid * 1024 + 512 + (c - 1536));
  }
  ushort4 b; b.x = f2bf(v.x); b.y = f2bf(v.y); b.z = f2bf(v.z); b.w = f2bf(v.w);
  if (c < 1536) *(ushort4*)(A0 + (size_t)n * 1536 + c) = b;
  else          *(ushort4*)(A1 + (size_t)n * 1024 + (c - 1024)) = b;
  if (n >= NB && c < 512) *(ushort4*)(A1 + (size_t)n * 1024 + c) = b;
}

// ---------------- 8-phase 256x256 GEMM + fused GRU epilogue ----------------
template <int K, bool DUAL>
__global__ __launch_bounds__(512, 2)
void gemm8(const u16* __restrict__ A, const u16* __restrict__ Bt,
           const float* __restrict__ bih, const float* __restrict__ bhh,
           const u16* __restrict__ hsrc, int hstride,
           u16* __restrict__ o1, u16* __restrict__ o2) {
  constexpr int NT = K / 64;
  __shared__ u16 S[4][16384];                        // [buf*2+mat], 32KB each, 128KB total

  int bid = blockIdx.x;
  int gidx = (bid & 7) * MB2 + (bid >> 3);           // XCD-contiguous
  int bm = gidx >> 3, bn = gidx & 7;

  int t = threadIdx.x;
  int lane = t & 63, w = t >> 6;
  int fr = lane & 15, fq = lane >> 4;
  int wm4 = w & 3, wn = w >> 2;                      // 4 row-groups x 2 col-groups

  const u16* Ap = A + (size_t)bm * 256 * K;
  const u16* Bp = Bt + (size_t)bn * 256 * K;

  f32x4 acc[2][2][2][4] = {};

  auto stage = [&](int kt2, int mat, int half, const u16* gsrc) {
#pragma unroll
    for (int l = 0; l < 2; ++l) {
      int row = half * 128 + l * 64 + (t >> 3);
      int gx = ((t & 7) * 16) ^ ((row & 7) << 4);    // inverse swizzle on global source
      const u16* g = gsrc + (size_t)row * K + kt2 * 64 + (gx >> 1);
      char* lp = (char*)&S[(kt2 & 1) * 2 + mat][0] + half * 16384 + l * 8192 + t * 16;
      __builtin_amdgcn_global_load_lds((const __attribute__((address_space(1))) void*)g,
                                       (__attribute__((address_space(3))) void*)lp, 16, 0, 0);
    }
  };
  auto ld = [&](int buf, int mat, int row, int kb) -> bf16x8 {
    return *(const bf16x8*)((const char*)&S[buf * 2 + mat][0] + row * 128 +
                            (kb ^ ((row & 7) << 4)));
  };

  // prologue ledger order: Ah0(0),Bh0(0),Bh1(0),Ah1(0),Ah0(1),Bh0(1)
  stage(0, 0, 0, Ap); stage(0, 1, 0, Bp); stage(0, 1, 1, Bp); stage(0, 0, 1, Ap);
  stage(1, 0, 0, Ap); stage(1, 1, 0, Bp);
  vmwaitc<8>();                                      // tile0 Ah0+Bh0 landed
  bar();

  for (int kt = 0; kt < NT; ++kt) {
    int cur = kt & 1;
#pragma unroll
    for (int q = 0; q < 4; ++q) {                    // (mh,nh) = (0,0),(0,1),(1,0),(1,1)
      const int mh = q >> 1, nh = q & 1;
      bf16x8 af[2][2], bv[4][2];
#pragma unroll
      for (int mi = 0; mi < 2; ++mi)
#pragma unroll
        for (int ks = 0; ks < 2; ++ks)
          af[mi][ks] = ld(cur, 0, mh * 128 + wm4 * 32 + mi * 16 + fr, ks * 64 + fq * 16);
#pragma unroll
      for (int nf = 0; nf < 4; ++nf)
#pragma unroll
        for (int ks = 0; ks < 2; ++ks)
          bv[nf][ks] = ld(cur, 1, nh * 128 + wn * 64 + nf * 16 + fr, ks * 64 + fq * 16);

      // stage exactly one half-tile into its just-freed slot
      if (q == 0)      { if (kt + 1 < NT) stage(kt + 1, 1, 1, Bp); }
      else if (q == 1) { if (kt + 1 < NT) stage(kt + 1, 0, 1, Ap); }
      else if (q == 2) { if (kt + 2 < NT) stage(kt + 2, 0, 0, Ap); }
      else             { if (kt + 2 < NT) stage(kt + 2, 1, 0, Bp); }

      bar();
      __builtin_amdgcn_s_setprio(1);
#pragma unroll
      for (int mi = 0; mi < 2; ++mi)
#pragma unroll
        for (int nf = 0; nf < 4; ++nf)
#pragma unroll
          for (int ks = 0; ks < 2; ++ks)
            acc[mh][nh][mi][nf] = __builtin_amdgcn_mfma_f32_16x16x32_bf16(
                af[mi][ks], bv[nf][ks], acc[mh][nh][mi][nf], 0, 0, 0);
      __builtin_amdgcn_s_setprio(0);

      // confirm next phase's half-tiles (counted, never 0 mid-loop)
      if (q == 0)      { if (kt + 1 < NT) vmwaitc<8>(); else vmwaitc<2>(); }
      else if (q == 1) { if (kt + 1 < NT) vmwaitc<8>(); else vmwaitc<0>(); }
      else if (q == 3) { if (kt + 1 < NT) { if (kt + 2 < NT) vmwaitc<8>(); else vmwaitc<4>(); } }
      bar();
    }
  }

  // ---- fused GRU epilogue: 4x4 quad transpose so each lane owns one row ----
  int gg = fr & 3, jj = fr >> 2;
  float bias[2][4];
#pragma unroll
  for (int nh = 0; nh < 2; ++nh)
#pragma unroll
    for (int nf = 0; nf < 4; ++nf) {
      int j = ((bn * 256 + nh * 128 + wn * 64 + nf * 16) >> 2) + jj;
      bias[nh][nf] = (gg == 0) ? bih[j] + bhh[j]
                   : (gg == 1) ? bih[512 + j] + bhh[512 + j]
                   : (gg == 2) ? bih[1024 + j] : bhh[1024 + j];
    }
#pragma unroll
  for (int mh = 0; mh < 2; ++mh)
#pragma unroll
    for (int nh = 0; nh < 2; ++nh)
#pragma unroll
      for (int mi = 0; mi < 2; ++mi) {
        int row = bm * 256 + mh * 128 + wm4 * 32 + mi * 16 + fq * 4 + gg;
#pragma unroll
        for (int nf = 0; nf < 4; ++nf) {
          float v[4], v1[4], v2[4];
#pragma unroll
          for (int r = 0; r < 4; ++r) v[r] = acc[mh][nh][mi][nf][r] + bias[nh][nf];
#pragma unroll
          for (int i = 0; i < 4; ++i) {
            float o = __shfl_xor(v[i ^ 2], 2);
            v1[i] = ((i ^ gg) & 2) ? o : v[i];
          }
#pragma unroll
          for (int i = 0; i < 4; ++i) {
            float o = __shfl_xor(v1[i ^ 1], 1);
            v2[i] = ((i ^ gg) & 1) ? o : v1[i];
          }
          if (row < NB) {
            int j = ((bn * 256 + nh * 128 + wn * 64 + nf * 16) >> 2) + jj;
            float rr = 1.f / (1.f + __expf(-v2[0]));
            float zz = 1.f / (1.f + __expf(-v2[1]));
            float nn = tanhf(fmaf(rr, v2[3], v2[2]));
            float h = bf2f(hsrc[(size_t)row * hstride + j]);
            float hp = (1.f - zz) * nn + zz * h;
            u16 hb = f2bf(hp);
            if (DUAL) { o1[(size_t)row * 1024 + j] = hb; o2[(size_t)row * 512 + j] = hb; }
            else      { o1[(size_t)row * 512 + j] = hb; }
          }
        }
      }
}

// ---------------- inverse map + final assembly ----------------
__global__ void init_inv(int* __restrict__ inv) {
  int i = blockIdx.x * 256 + threadIdx.x;
  if (i < NNODES) inv[i] = -1;
}
__global__ void set_inv(const int* __restrict__ nids, int* __restrict__ inv) {
  int i = blockIdx.x * 256 + threadIdx.x;
  if (i < NB) inv[nids[i]] = i;
}
__global__ void assemble(const float4* __restrict__ dyn4, const u16* __restrict__ H0,
                         const u16* __restrict__ H1, const int* __restrict__ inv,
                         float4* __restrict__ out4) {
  const size_t total = (size_t)NNODES * 256;
  for (size_t i = (size_t)blockIdx.x * 256 + threadIdx.x; i < total;
       i += (size_t)gridDim.x * 256) {
    int row = (int)(i >> 8);
    int n = inv[row];
    if (n < 0) {
      out4[i] = dyn4[i];
    } else {
      int c = (int)(i & 255) * 4;
      const u16* s = (c < 512) ? H0 + (size_t)n * 512 + c : H1 + (size_t)n * 512 + (c - 512);
      float4 v; v.x = bf2f(s[0]); v.y = bf2f(s[1]); v.z = bf2f(s[2]); v.w = bf2f(s[3]);
      out4[i] = v;
    }
  }
}

extern "C" void kernel_launch(void* const* d_in, const int* in_sizes, int n_in,
                              void* d_out, int out_size, void* d_ws, size_t ws_size,
                              hipStream_t stream) {
  const float* conv = (const float*)d_in[0];
  const float* stat = (const float*)d_in[1];
  const float* dyn  = (const float*)d_in[2];
  const float* Wih0 = (const float*)d_in[3];
  const float* Whh0 = (const float*)d_in[4];
  const float* bih0 = (const float*)d_in[5];
  const float* bhh0 = (const float*)d_in[6];
  const float* Wih1 = (const float*)d_in[7];
  const float* Whh1 = (const float*)d_in[8];
  const float* bih1 = (const float*)d_in[9];
  const float* bhh1 = (const float*)d_in[10];
  const int*   nids = (const int*)d_in[11];

  char* ws = (char*)d_ws;
  u16* A0  = (u16*)ws;                        // 20224*1536*2 = 62,128,128
  u16* H0b = (u16*)(ws + 62128128);           // 20224*512*2  = 20,709,376
  u16* Bt0 = (u16*)(ws + 82837504);           // 2048*1536*2  =  6,291,456
  u16* Bt1 = (u16*)(ws + 89128960);           // 2048*1024*2  =  4,194,304
  u16* H1  = (u16*)ws;                        // alias A0 (dead after gemm0)
  int* inv = (int*)(ws + 82837504);           // alias Bt0 (dead after gemm0)
  u16* A1  = (u16*)d_out;                     // 20224*1024*2 = 41.4MB scratch in out

  prep_bt0i<<<3072, 256, 0, stream>>>(Wih0, Whh0, Bt0);
  prep_bt1i<<<2048, 256, 0, stream>>>(Wih1, Whh1, Bt1);
  prep_a<<<(MP2 * 512) / 256, 256, 0, stream>>>(conv, stat, dyn, nids, A0, A1);

  gemm8<1536, true><<<MB2 * 8, 512, 0, stream>>>(A0, Bt0, bih0, bhh0,
                                                 A0 + 1024, 1536, A1, H0b);

  init_inv<<<(NNODES + 255) / 256, 256, 0, stream>>>(inv);
  set_inv<<<(NB + 255) / 256, 256, 0, stream>>>(nids, inv);

  gemm8<1024, false><<<MB2 * 8, 512, 0, stream>>>(A1, Bt1, bih1, bhh1,
                                                  A1 + 512, 1024, H1, (u16*)nullptr);

  assemble<<<4096, 256, 0, stream>>>((const float4*)dyn, H0b, H1, inv, (float4*)d_out);
}

// Round 4
// 510.199 us; speedup vs baseline: 1.3682x; 1.0336x over previous
//
#include <hip/hip_runtime.h>

#define NB 20000
#define NNODES 100000
#define MB2 79              // ceil(20000/256)
#define MP2 (MB2*256)       // 20224 padded rows
#define NBITW 3125          // ceil(100000/32)
#define NGEMM (MB2*8)       // 632 gemm blocks
#define NCOPY 1416          // copy blocks appended per gemm dispatch

typedef unsigned short u16;
typedef __bf16 bf16x8 __attribute__((ext_vector_type(8)));
typedef float f32x4 __attribute__((ext_vector_type(4)));

__device__ __forceinline__ u16 f2bf(float f) {
  union { float f; unsigned u; } v; v.f = f;
  unsigned r = v.u + 0x7fffu + ((v.u >> 16) & 1u);
  return (u16)(r >> 16);
}
__device__ __forceinline__ float bf2f(u16 b) {
  union { unsigned u; float f; } v; v.u = ((unsigned)b) << 16;
  return v.f;
}

template <int N> __device__ __forceinline__ void vmwaitc() {
  if constexpr (N == 0) asm volatile("s_waitcnt vmcnt(0)" ::: "memory");
  else if constexpr (N == 2) asm volatile("s_waitcnt vmcnt(2)" ::: "memory");
  else if constexpr (N == 4) asm volatile("s_waitcnt vmcnt(4)" ::: "memory");
  else asm volatile("s_waitcnt vmcnt(8)" ::: "memory");
  __builtin_amdgcn_sched_barrier(0);
}
__device__ __forceinline__ void bar() {
  __builtin_amdgcn_sched_barrier(0);
  __builtin_amdgcn_s_barrier();
  __builtin_amdgcn_sched_barrier(0);
}

// ---------------- weight prep: interleaved B^T rows jg = j*4 + gate {r,z,i_n,h_n} ----------
__global__ void prep_bt0i(const float* __restrict__ Wih, const float* __restrict__ Whh,
                          u16* __restrict__ Bt) {
  int idx = blockIdx.x * 256 + threadIdx.x;          // 2048*384
  if (idx >= 2048 * 384) return;
  int jg = idx / 384;
  int k = (idx % 384) * 4;
  int j = jg >> 2, g = jg & 3;
  float4 v = make_float4(0.f, 0.f, 0.f, 0.f);
  if (g < 2) {
    int row = g * 512 + j;
    v = (k < 1024) ? *(const float4*)(Wih + (size_t)row * 1024 + k)
                   : *(const float4*)(Whh + (size_t)row * 512 + (k - 1024));
  } else if (g == 2) {
    if (k < 1024) v = *(const float4*)(Wih + (size_t)(1024 + j) * 1024 + k);
  } else {
    if (k >= 1024) v = *(const float4*)(Whh + (size_t)(1024 + j) * 512 + (k - 1024));
  }
  ushort4 b; b.x = f2bf(v.x); b.y = f2bf(v.y); b.z = f2bf(v.z); b.w = f2bf(v.w);
  *(ushort4*)(Bt + (size_t)jg * 1536 + k) = b;
}

__global__ void prep_bt1i(const float* __restrict__ Wih, const float* __restrict__ Whh,
                          u16* __restrict__ Bt) {
  int idx = blockIdx.x * 256 + threadIdx.x;          // 2048*256
  if (idx >= 2048 * 256) return;
  int jg = idx / 256;
  int k = (idx % 256) * 4;
  int j = jg >> 2, g = jg & 3;
  float4 v = make_float4(0.f, 0.f, 0.f, 0.f);
  if (g < 2) {
    int row = g * 512 + j;
    v = (k < 512) ? *(const float4*)(Wih + (size_t)row * 512 + k)
                  : *(const float4*)(Whh + (size_t)row * 512 + (k - 512));
  } else if (g == 2) {
    if (k < 512) v = *(const float4*)(Wih + (size_t)(1024 + j) * 512 + k);
  } else {
    if (k >= 512) v = *(const float4*)(Whh + (size_t)(1024 + j) * 512 + (k - 512));
  }
  ushort4 b; b.x = f2bf(v.x); b.y = f2bf(v.y); b.z = f2bf(v.z); b.w = f2bf(v.w);
  *(ushort4*)(Bt + (size_t)jg * 1024 + k) = b;
}

// ---------------- A prep ----------------
__global__ void prep_a(const float* __restrict__ conv, const float* __restrict__ stat,
                       const float* __restrict__ dyn, const int* __restrict__ nids,
                       u16* __restrict__ A0, u16* __restrict__ A1) {
  int idx = blockIdx.x * 256 + threadIdx.x;          // MP2*512
  int n = idx >> 9;
  int c = (idx & 511) * 4;
  if (n >= MP2) return;
  float4 v = make_float4(0.f, 0.f, 0.f, 0.f);
  if (n < NB) {
    size_t nid = (size_t)nids[n];
    if (c < 512)        v = *(const float4*)(conv + (size_t)n * 512 + c);
    else if (c < 1024)  v = *(const float4*)(stat + nid * 512 + (c - 512));
    else if (c < 1536)  v = *(const float4*)(dyn + nid * 1024 + (c - 1024));
    else                v = *(const float4*)(dyn + nid * 1024 + 512 + (c - 1536));
  }
  ushort4 b; b.x = f2bf(v.x); b.y = f2bf(v.y); b.z = f2bf(v.z); b.w = f2bf(v.w);
  if (c < 1536) *(ushort4*)(A0 + (size_t)n * 1536 + c) = b;
  else          *(ushort4*)(A1 + (size_t)n * 1024 + (c - 1024)) = b;
  if (n >= NB && c < 512) *(ushort4*)(A1 + (size_t)n * 1024 + c) = b;
}

// ---------------- bitmap ----------------
__global__ void zero_bits(unsigned* __restrict__ bits) {
  int i = blockIdx.x * 256 + threadIdx.x;
  if (i < NBITW) bits[i] = 0;
}
__global__ void set_bits(const int* __restrict__ nids, unsigned* __restrict__ bits) {
  int i = blockIdx.x * 256 + threadIdx.x;
  if (i < NB) {
    int nid = nids[i];
    atomicOr(&bits[nid >> 5], 1u << (nid & 31));
  }
}

// ---------------- 8-phase 256x256 GEMM + fused GRU epilogue + hybrid table copy ----------
template <int K, int LAYER>
__global__ __launch_bounds__(512, 2)
void gemm8(const u16* __restrict__ A, const u16* __restrict__ Bt,
           const float* __restrict__ bih, const float* __restrict__ bhh,
           const u16* __restrict__ hsrc, int hstride, const int* __restrict__ nids,
           u16* __restrict__ a1out, float* __restrict__ out,
           const float4* __restrict__ src4, float4* __restrict__ dst4,
           const unsigned* __restrict__ bits, long cbeg, long cend) {
  constexpr int NT = K / 64;
  __shared__ u16 S[4][16384];                        // 128KB

  // ---- hybrid copy blocks: drain idle BW / scheduling tail during GEMM ----
  if (blockIdx.x >= NGEMM) {
    long cb = blockIdx.x - NGEMM;
    long total = cend - cbeg;
    long per = (total + NCOPY - 1) / NCOPY;
    long s = cbeg + cb * per;
    long e = s + per; if (e > cend) e = cend;
    long i = s + threadIdx.x;
    for (; i + 1536 < e; i += 2048) {
      float4 a0 = src4[i], a1 = src4[i + 512], a2 = src4[i + 1024], a3 = src4[i + 1536];
      int r0 = (int)(i >> 8), r1 = (int)((i + 512) >> 8),
          r2 = (int)((i + 1024) >> 8), r3 = (int)((i + 1536) >> 8);
      if (!((bits[r0 >> 5] >> (r0 & 31)) & 1u)) dst4[i] = a0;
      if (!((bits[r1 >> 5] >> (r1 & 31)) & 1u)) dst4[i + 512] = a1;
      if (!((bits[r2 >> 5] >> (r2 & 31)) & 1u)) dst4[i + 1024] = a2;
      if (!((bits[r3 >> 5] >> (r3 & 31)) & 1u)) dst4[i + 1536] = a3;
    }
    for (; i < e; i += 512) {
      int row = (int)(i >> 8);
      if (!((bits[row >> 5] >> (row & 31)) & 1u)) dst4[i] = src4[i];
    }
    return;
  }

  int bid = blockIdx.x;
  int gidx = (bid & 7) * MB2 + (bid >> 3);           // XCD-contiguous
  int bm = gidx >> 3, bn = gidx & 7;

  int t = threadIdx.x;
  int lane = t & 63, w = t >> 6;
  int fr = lane & 15, fq = lane >> 4;
  int wm4 = w & 3, wn = w >> 2;                      // 4 row-groups x 2 col-groups

  const u16* Ap = A + (size_t)bm * 256 * K;
  const u16* Bp = Bt + (size_t)bn * 256 * K;

  f32x4 acc[2][2][2][4] = {};

  auto stage = [&](int kt2, int mat, int half, const u16* gsrc) {
#pragma unroll
    for (int l = 0; l < 2; ++l) {
      int row = half * 128 + l * 64 + (t >> 3);
      int gx = ((t & 7) * 16) ^ ((row & 7) << 4);    // inverse swizzle on global source
      const u16* g = gsrc + (size_t)row * K + kt2 * 64 + (gx >> 1);
      char* lp = (char*)&S[(kt2 & 1) * 2 + mat][0] + half * 16384 + l * 8192 + t * 16;
      __builtin_amdgcn_global_load_lds((const __attribute__((address_space(1))) void*)g,
                                       (__attribute__((address_space(3))) void*)lp, 16, 0, 0);
    }
  };
  auto ld = [&](int buf, int mat, int row, int kb) -> bf16x8 {
    return *(const bf16x8*)((const char*)&S[buf * 2 + mat][0] + row * 128 +
                            (kb ^ ((row & 7) << 4)));
  };

  stage(0, 0, 0, Ap); stage(0, 1, 0, Bp); stage(0, 1, 1, Bp); stage(0, 0, 1, Ap);
  stage(1, 0, 0, Ap); stage(1, 1, 0, Bp);
  vmwaitc<8>();
  bar();

  for (int kt = 0; kt < NT; ++kt) {
    int cur = kt & 1;
#pragma unroll
    for (int q = 0; q < 4; ++q) {                    // (mh,nh)
      const int mh = q >> 1, nh = q & 1;
      bf16x8 af[2][2], bv[4][2];
#pragma unroll
      for (int mi = 0; mi < 2; ++mi)
#pragma unroll
        for (int ks = 0; ks < 2; ++ks)
          af[mi][ks] = ld(cur, 0, mh * 128 + wm4 * 32 + mi * 16 + fr, ks * 64 + fq * 16);
#pragma unroll
      for (int nf = 0; nf < 4; ++nf)
#pragma unroll
        for (int ks = 0; ks < 2; ++ks)
          bv[nf][ks] = ld(cur, 1, nh * 128 + wn * 64 + nf * 16 + fr, ks * 64 + fq * 16);

      if (q == 0)      { if (kt + 1 < NT) stage(kt + 1, 1, 1, Bp); }
      else if (q == 1) { if (kt + 1 < NT) stage(kt + 1, 0, 1, Ap); }
      else if (q == 2) { if (kt + 2 < NT) stage(kt + 2, 0, 0, Ap); }
      else             { if (kt + 2 < NT) stage(kt + 2, 1, 0, Bp); }

      bar();
      __builtin_amdgcn_s_setprio(1);
#pragma unroll
      for (int mi = 0; mi < 2; ++mi)
#pragma unroll
        for (int nf = 0; nf < 4; ++nf)
#pragma unroll
          for (int ks = 0; ks < 2; ++ks)
            acc[mh][nh][mi][nf] = __builtin_amdgcn_mfma_f32_16x16x32_bf16(
                af[mi][ks], bv[nf][ks], acc[mh][nh][mi][nf], 0, 0, 0);
      __builtin_amdgcn_s_setprio(0);

      if (q == 0)      { if (kt + 1 < NT) vmwaitc<8>(); else vmwaitc<2>(); }
      else if (q == 1) { if (kt + 1 < NT) vmwaitc<8>(); else vmwaitc<0>(); }
      else if (q == 3) { if (kt + 1 < NT) { if (kt + 2 < NT) vmwaitc<8>(); else vmwaitc<4>(); } }
      bar();
    }
  }

  // ---- fused GRU epilogue: quad transpose, direct f32 writes to out ----
  int gg = fr & 3, jj = fr >> 2;
  float bias[2][4];
#pragma unroll
  for (int nh = 0; nh < 2; ++nh)
#pragma unroll
    for (int nf = 0; nf < 4; ++nf) {
      int j = ((bn * 256 + nh * 128 + wn * 64 + nf * 16) >> 2) + jj;
      bias[nh][nf] = (gg == 0) ? bih[j] + bhh[j]
                   : (gg == 1) ? bih[512 + j] + bhh[512 + j]
                   : (gg == 2) ? bih[1024 + j] : bhh[1024 + j];
    }
#pragma unroll
  for (int mh = 0; mh < 2; ++mh)
#pragma unroll
    for (int nh = 0; nh < 2; ++nh)
#pragma unroll
      for (int mi = 0; mi < 2; ++mi) {
        int row = bm * 256 + mh * 128 + wm4 * 32 + mi * 16 + fq * 4 + gg;
#pragma unroll
        for (int nf = 0; nf < 4; ++nf) {
          float v[4], v1[4], v2[4];
#pragma unroll
          for (int r = 0; r < 4; ++r) v[r] = acc[mh][nh][mi][nf][r] + bias[nh][nf];
#pragma unroll
          for (int i = 0; i < 4; ++i) {
            float o = __shfl_xor(v[i ^ 2], 2);
            v1[i] = ((i ^ gg) & 2) ? o : v[i];
          }
#pragma unroll
          for (int i = 0; i < 4; ++i) {
            float o = __shfl_xor(v1[i ^ 1], 1);
            v2[i] = ((i ^ gg) & 1) ? o : v1[i];
          }
          if (row < NB) {
            int j = ((bn * 256 + nh * 128 + wn * 64 + nf * 16) >> 2) + jj;
            float rr = 1.f / (1.f + __expf(-v2[0]));
            float zz = 1.f / (1.f + __expf(-v2[1]));
            float nn = tanhf(fmaf(rr, v2[3], v2[2]));
            float h = bf2f(hsrc[(size_t)row * hstride + j]);
            float hp = (1.f - zz) * nn + zz * h;
            if (LAYER == 0) a1out[(size_t)row * 1024 + j] = f2bf(hp);
            out[(size_t)nids[row] * 1024 + LAYER * 512 + j] = hp;
          }
        }
      }
}

// ---------------- tail copy ----------------
__global__ void copy_tail(const float4* __restrict__ src, float4* __restrict__ dst,
                          const unsigned* __restrict__ bits, long cbeg, long cend) {
  for (long i = cbeg + (long)blockIdx.x * 256 + threadIdx.x; i < cend;
       i += (long)gridDim.x * 256) {
    int row = (int)(i >> 8);
    if (!((bits[row >> 5] >> (row & 31)) & 1u)) dst[i] = src[i];
  }
}

extern "C" void kernel_launch(void* const* d_in, const int* in_sizes, int n_in,
                              void* d_out, int out_size, void* d_ws, size_t ws_size,
                              hipStream_t stream) {
  const float* conv = (const float*)d_in[0];
  const float* stat = (const float*)d_in[1];
  const float* dyn  = (const float*)d_in[2];
  const float* Wih0 = (const float*)d_in[3];
  const float* Whh0 = (const float*)d_in[4];
  const float* bih0 = (const float*)d_in[5];
  const float* bhh0 = (const float*)d_in[6];
  const float* Wih1 = (const float*)d_in[7];
  const float* Whh1 = (const float*)d_in[8];
  const float* bih1 = (const float*)d_in[9];
  const float* bhh1 = (const float*)d_in[10];
  const int*   nids = (const int*)d_in[11];
  float* out = (float*)d_out;

  char* ws = (char*)d_ws;
  u16* A0  = (u16*)ws;                        // 20224*1536*2 = 62,128,128
  u16* A1  = (u16*)(ws + 62128128);           // 20224*1024*2 = 41,418,752
  u16* Bt0 = (u16*)(ws + 103546880);          // 6,291,456
  u16* Bt1 = (u16*)(ws + 109838336);          // 4,194,304
  unsigned* bits = (unsigned*)(ws + 114032640);

  zero_bits<<<(NBITW + 255) / 256, 256, 0, stream>>>(bits);
  set_bits<<<(NB + 255) / 256, 256, 0, stream>>>(nids, bits);
  prep_bt0i<<<3072, 256, 0, stream>>>(Wih0, Whh0, Bt0);
  prep_bt1i<<<2048, 256, 0, stream>>>(Wih1, Whh1, Bt1);
  prep_a<<<(MP2 * 512) / 256, 256, 0, stream>>>(conv, stat, dyn, nids, A0, A1);

  const long E_ROW = 256;                     // float4 per table row
  gemm8<1536, 0><<<NGEMM + NCOPY, 512, 0, stream>>>(
      A0, Bt0, bih0, bhh0, A0 + 1024, 1536, nids, A1, out,
      (const float4*)dyn, (float4*)out, bits, 0L, 55000L * E_ROW);
  gemm8<1024, 1><<<NGEMM + NCOPY, 512, 0, stream>>>(
      A1, Bt1, bih1, bhh1, A1 + 512, 1024, nids, (u16*)nullptr, out,
      (const float4*)dyn, (float4*)out, bits, 55000L * E_ROW, 92000L * E_ROW);
  copy_tail<<<1024, 256, 0, stream>>>((const float4*)dyn, (float4*)out, bits,
                                      92000L * E_ROW, (long)NNODES * E_ROW);
}